// Round 4
// baseline (249.773 us; speedup 1.0000x reference)
//
#include <hip/hip_runtime.h>
#include <stdint.h>
#include <stddef.h>

#define EPS   1e-5f
#define CINCH 128
#define CI    64
#define NPIX  4096
#define KSPL  8
#define LOG2E 1.44269504088896340736f

typedef __bf16 bf16_t;
typedef _Float16 f16_t;
typedef bf16_t bf16x8 __attribute__((ext_vector_type(8)));
typedef f16_t  f16x8  __attribute__((ext_vector_type(8)));
typedef float  f32x4  __attribute__((ext_vector_type(4)));

typedef __attribute__((address_space(3))) unsigned int lds_u32;
typedef __attribute__((address_space(1))) const unsigned int glb_u32;

__device__ __forceinline__ f32x4 mfma16(bf16x8 a, bf16x8 b, f32x4 c) {
  return __builtin_amdgcn_mfma_f32_16x16x32_bf16(a, b, c, 0, 0, 0);
}
__device__ __forceinline__ f32x4 fzero4() {
  f32x4 z = {0.f, 0.f, 0.f, 0.f};
  return z;
}
__device__ __forceinline__ void gload16(const void* g, void* l) {
  __builtin_amdgcn_global_load_lds((glb_u32*)g, (lds_u32*)l, 16, 0, 0);
}

// ---------------------------------------------------------------------------
// Workspace (MiB offsets):
//   thetaT_h [B][N][64] bf16 (x LOG2E)   0
//   thetaT_l [B][N][64] bf16 (x LOG2E)   2
//   phiT_h   [B][N][64] bf16 swizzled    4
//   phiT_l   [B][N][64] bf16 swizzled    6
//   g_cm     [B][64][N] bf16 plain       8
//   Opart    [B][8][N][64] f16          10   (16 MiB)
//   ml       [B][8][N][2]  f32          26   (1 MiB)   -> 27 MiB total
// phi global swizzle: within each 128B key-row, byte = (c*2) ^ ((key&7)<<4)
// ---------------------------------------------------------------------------

// ===================== stage 1a: theta projection + x1 concat ===============
// grid (128,4), 256 thr. x-tile LDS-staged (coalesced); 3 blocks/CU.
__global__ __launch_bounds__(256) void proj_theta(
    const float* __restrict__ x1,
    const float* __restrict__ w,  const float* __restrict__ bb,
    const float* __restrict__ gm, const float* __restrict__ bt,
    const float* __restrict__ mn, const float* __restrict__ vr,
    bf16_t* __restrict__ thetaT_h, bf16_t* __restrict__ thetaT_l,
    float* __restrict__ out)
{
  __shared__ float wT[CINCH][CI];                       // 32 KiB
  __shared__ float bfold[CI];
  __shared__ __align__(16) char ubuf[CINCH * 32 * 4];   // 16 KiB: xs / tileF
  float (*xs)[32]    = (float(*)[32])ubuf;
  float (*tileF)[68] = (float(*)[68])ubuf;

  const int tid = threadIdx.x;
  const int b   = blockIdx.y;
  const int n0  = blockIdx.x * 32;

  for (int idx = tid; idx < CI * CINCH; idx += 256) {
    const int o = idx & 63, c = idx >> 6;
    const float sc = gm[o] * rsqrtf(vr[o] + EPS);
    wT[c][o] = w[o * CINCH + c] * sc * LOG2E;
    if (c == 0) bfold[o] = (bb[o] * sc + bt[o] - mn[o] * sc) * LOG2E;
  }

  // stage x tile [128c][32px] + fused concat copy
  {
    const float* xsrc = x1 + (size_t)b * CINCH * NPIX + n0;
    float* osrc = out + ((size_t)b * 256 + 128) * NPIX + n0;
#pragma unroll
    for (int i = 0; i < 4; ++i) {
      const int idx = i * 256 + tid;
      const int c = idx >> 3, p = idx & 7;
      const f32x4 v = *(const f32x4*)(xsrc + (size_t)c * NPIX + p * 4);
      *(f32x4*)&xs[c][p * 4] = v;
      *(f32x4*)(osrc + (size_t)c * NPIX + p * 4) = v;
    }
  }
  __syncthreads();

  const int px = tid & 31;
  const int og = tid >> 5;
  float acc[8];
#pragma unroll
  for (int j = 0; j < 8; ++j) acc[j] = 0.f;

#pragma unroll 4
  for (int c0 = 0; c0 < CINCH; c0 += 4) {
    float xv[4];
#pragma unroll
    for (int cc = 0; cc < 4; ++cc) xv[cc] = xs[c0 + cc][px];
#pragma unroll
    for (int cc = 0; cc < 4; ++cc) {
      const f32x4 w0 = *(const f32x4*)&wT[c0 + cc][og * 8];
      const f32x4 w1 = *(const f32x4*)&wT[c0 + cc][og * 8 + 4];
#pragma unroll
      for (int j = 0; j < 4; ++j) {
        acc[j]     += w0[j] * xv[cc];
        acc[j + 4] += w1[j] * xv[cc];
      }
    }
  }
  __syncthreads();   // xs reads done before aliased tileF writes
#pragma unroll
  for (int j = 0; j < 8; ++j) tileF[px][og * 8 + j] = acc[j] + bfold[og * 8 + j];
  __syncthreads();

  {
    const int px2 = tid >> 3, ogs = tid & 7;
    bf16x8 hv, lv;
#pragma unroll
    for (int j = 0; j < 8; ++j) {
      const float v = tileF[px2][ogs * 8 + j];
      const bf16_t h = (bf16_t)v;
      hv[j] = h;
      lv[j] = (bf16_t)(v - (float)h);
    }
    const size_t base = ((size_t)b * NPIX + n0 + px2) * CI + ogs * 8;
    *(bf16x8*)(thetaT_h + base) = hv;
    *(bf16x8*)(thetaT_l + base) = lv;
  }
}

// ===================== stage 1b: phi projection (swizzled h/l) ==============
__global__ __launch_bounds__(256) void proj_phi(
    const float* __restrict__ x2,
    const float* __restrict__ w,  const float* __restrict__ bb,
    const float* __restrict__ gm, const float* __restrict__ bt,
    const float* __restrict__ mn, const float* __restrict__ vr,
    bf16_t* __restrict__ phiT_h, bf16_t* __restrict__ phiT_l)
{
  __shared__ float wT[CINCH][CI];
  __shared__ float bfold[CI];
  __shared__ __align__(16) char ubuf[CINCH * 32 * 4];
  float (*xs)[32]    = (float(*)[32])ubuf;
  float (*tileF)[68] = (float(*)[68])ubuf;

  const int tid = threadIdx.x;
  const int b   = blockIdx.y;
  const int n0  = blockIdx.x * 32;

  for (int idx = tid; idx < CI * CINCH; idx += 256) {
    const int o = idx & 63, c = idx >> 6;
    const float sc = gm[o] * rsqrtf(vr[o] + EPS);
    wT[c][o] = w[o * CINCH + c] * sc;
    if (c == 0) bfold[o] = bb[o] * sc + bt[o] - mn[o] * sc;
  }
  {
    const float* xsrc = x2 + (size_t)b * CINCH * NPIX + n0;
#pragma unroll
    for (int i = 0; i < 4; ++i) {
      const int idx = i * 256 + tid;
      const int c = idx >> 3, p = idx & 7;
      *(f32x4*)&xs[c][p * 4] = *(const f32x4*)(xsrc + (size_t)c * NPIX + p * 4);
    }
  }
  __syncthreads();

  const int px = tid & 31;
  const int og = tid >> 5;
  float acc[8];
#pragma unroll
  for (int j = 0; j < 8; ++j) acc[j] = 0.f;

#pragma unroll 4
  for (int c0 = 0; c0 < CINCH; c0 += 4) {
    float xv[4];
#pragma unroll
    for (int cc = 0; cc < 4; ++cc) xv[cc] = xs[c0 + cc][px];
#pragma unroll
    for (int cc = 0; cc < 4; ++cc) {
      const f32x4 w0 = *(const f32x4*)&wT[c0 + cc][og * 8];
      const f32x4 w1 = *(const f32x4*)&wT[c0 + cc][og * 8 + 4];
#pragma unroll
      for (int j = 0; j < 4; ++j) {
        acc[j]     += w0[j] * xv[cc];
        acc[j + 4] += w1[j] * xv[cc];
      }
    }
  }
  __syncthreads();
#pragma unroll
  for (int j = 0; j < 8; ++j) tileF[px][og * 8 + j] = acc[j] + bfold[og * 8 + j];
  __syncthreads();

  {
    const int px2 = tid >> 3, ogs = tid & 7;
    const int n = n0 + px2;
    bf16x8 hv, lv;
#pragma unroll
    for (int j = 0; j < 8; ++j) {
      const float v = tileF[px2][ogs * 8 + j];
      const bf16_t h = (bf16_t)v;
      hv[j] = h;
      lv[j] = (bf16_t)(v - (float)h);
    }
    const size_t rowb = ((size_t)b * NPIX + n) * 128;
    const int byte = (ogs * 16) ^ ((n & 7) << 4);
    *(bf16x8*)((char*)phiT_h + rowb + byte) = hv;
    *(bf16x8*)((char*)phiT_l + rowb + byte) = lv;
  }
}

// ===================== stage 1c: g projection (plain [c][m]) ================
__global__ __launch_bounds__(256) void proj_g(
    const float* __restrict__ x2,
    const float* __restrict__ w,  const float* __restrict__ bb,
    const float* __restrict__ gm, const float* __restrict__ bt,
    const float* __restrict__ mn, const float* __restrict__ vr,
    bf16_t* __restrict__ g_cm)
{
  __shared__ float wT[CINCH][CI];
  __shared__ float bfold[CI];
  __shared__ __align__(16) char ubuf[CINCH * 32 * 4];
  float (*xs)[32] = (float(*)[32])ubuf;
  float (*gT)[33] = (float(*)[33])ubuf;     // [64][33] = 8.4 KiB

  const int tid = threadIdx.x;
  const int b   = blockIdx.y;
  const int n0  = blockIdx.x * 32;

  for (int idx = tid; idx < CI * CINCH; idx += 256) {
    const int o = idx & 63, c = idx >> 6;
    const float sc = gm[o] * rsqrtf(vr[o] + EPS);
    wT[c][o] = w[o * CINCH + c] * sc;
    if (c == 0) bfold[o] = bb[o] * sc + bt[o] - mn[o] * sc;
  }
  {
    const float* xsrc = x2 + (size_t)b * CINCH * NPIX + n0;
#pragma unroll
    for (int i = 0; i < 4; ++i) {
      const int idx = i * 256 + tid;
      const int c = idx >> 3, p = idx & 7;
      *(f32x4*)&xs[c][p * 4] = *(const f32x4*)(xsrc + (size_t)c * NPIX + p * 4);
    }
  }
  __syncthreads();

  const int px = tid & 31;
  const int og = tid >> 5;
  float acc[8];
#pragma unroll
  for (int j = 0; j < 8; ++j) acc[j] = 0.f;

#pragma unroll 4
  for (int c0 = 0; c0 < CINCH; c0 += 4) {
    float xv[4];
#pragma unroll
    for (int cc = 0; cc < 4; ++cc) xv[cc] = xs[c0 + cc][px];
#pragma unroll
    for (int cc = 0; cc < 4; ++cc) {
      const f32x4 w0 = *(const f32x4*)&wT[c0 + cc][og * 8];
      const f32x4 w1 = *(const f32x4*)&wT[c0 + cc][og * 8 + 4];
#pragma unroll
      for (int j = 0; j < 4; ++j) {
        acc[j]     += w0[j] * xv[cc];
        acc[j + 4] += w1[j] * xv[cc];
      }
    }
  }
  __syncthreads();
#pragma unroll
  for (int j = 0; j < 8; ++j) gT[og * 8 + j][px] = acc[j] + bfold[og * 8 + j];
  __syncthreads();

  {
    const int c = tid & 63, mgp = tid >> 6;
    bf16x8 gv;
#pragma unroll
    for (int j = 0; j < 8; ++j) gv[j] = (bf16_t)gT[c][mgp * 8 + j];
    *(bf16x8*)(g_cm + ((size_t)b * CI + c) * NPIX + n0 + mgp * 8) = gv;
  }
}

// ========================= stage 2: flash attention =========================
// Grid: 512 = B(4) x qt(16) x ks(8). Block: 512 (8 waves x 32 q).
// KBLK=64, double-buffered K (gload_lds) + V (reg-staged, XOR-swizzled).
// 2 blocks/CU, 16 waves/CU. LDS exactly 80 KiB.
__global__ __launch_bounds__(512, 4) void flash_attn(
    const bf16_t* __restrict__ thetaT_h, const bf16_t* __restrict__ thetaT_l,
    const bf16_t* __restrict__ phiT_h,   const bf16_t* __restrict__ phiT_l,
    const bf16_t* __restrict__ g_cm,
    f16_t* __restrict__ Opart, float* __restrict__ mlbuf)
{
  __shared__ __attribute__((aligned(16))) char sK[2][16384];  // [H 8K | L 8K]
  __shared__ __attribute__((aligned(16))) char sV[2][8192];   // [c][m] swz
  __shared__ __attribute__((aligned(16))) char sP[8][4096];   // per-wave, swz

  const int tid  = threadIdx.x;
  const int lane = tid & 63;
  const int wid  = tid >> 6;
  const int lrow = lane & 15;
  const int lhi  = lane >> 4;

  const int wg = blockIdx.x;
  const int b  = wg >> 7;
  const int rr = wg & 127;
  const int qt = rr >> 3;
  const int ks = rr & 7;
  const int q0 = qt * 256 + wid * 32;
  const int tg0 = ks * 8;                 // 8 tiles of 64 keys

  const char* const srcPHb = (const char*)phiT_h + ((size_t)b * NPIX) * 128;
  const char* const srcPLb = (const char*)phiT_l + ((size_t)b * NPIX) * 128;
  const char* const srcVb  = (const char*)g_cm + (size_t)b * CI * NPIX * 2;

  const int vc = tid >> 3, vp = tid & 7;  // V staging: row c, 16B part

  auto stageK = [&](int buf, int tg) {
    const size_t rb = (size_t)tg * 8192;
    gload16(srcPHb + rb + tid * 16, sK[buf] + tid * 16);
    gload16(srcPLb + rb + tid * 16, sK[buf] + 8192 + tid * 16);
  };
  auto loadV = [&](int tg) {
    return *(const f32x4*)(srcVb + ((size_t)vc * NPIX + tg * 64 + vp * 8) * 2);
  };
  auto writeV = [&](int buf, f32x4 v) {
    *(f32x4*)(sV[buf] + vc * 128 + ((vp * 16) ^ ((vc & 7) << 4))) = v;
  };

  // Q fragments (theta pre-scaled by LOG2E), h & l splits
  bf16x8 qh[2][2], qlv[2][2];
  {
    const bf16_t* qbh = thetaT_h + ((size_t)b * NPIX + q0 + lrow) * CI + lhi * 8;
    const bf16_t* qbl = thetaT_l + ((size_t)b * NPIX + q0 + lrow) * CI + lhi * 8;
#pragma unroll
    for (int nt = 0; nt < 2; ++nt)
#pragma unroll
      for (int kk = 0; kk < 2; ++kk) {
        qh[nt][kk]  = *(const bf16x8*)(qbh + nt * 16 * CI + kk * 32);
        qlv[nt][kk] = *(const bf16x8*)(qbl + nt * 16 * CI + kk * 32);
      }
  }

  f32x4 oacc[2][4];
#pragma unroll
  for (int a = 0; a < 2; ++a)
#pragma unroll
    for (int c = 0; c < 4; ++c) oacc[a][c] = fzero4();

  float m_run[2] = {-1e30f, -1e30f};
  float l_run[2] = {0.f, 0.f};

  char* const Pw = sP[wid];
  const int pswz[2] = {(lrow & 7) << 4, ((lrow & 7) << 4)};  // row-swz for P rows q=nt*16+lrow

  stageK(0, tg0);
  writeV(0, loadV(tg0));
  __syncthreads();

  for (int t = 0; t < 8; ++t) {
    const int cur = t & 1;
    const bool more = (t < 7);
    f32x4 vnext;
    if (more) { stageK(cur ^ 1, tg0 + t + 1); vnext = loadV(tg0 + t + 1); }

    const char* const sKH = sK[cur];
    const char* const sKL = sK[cur] + 8192;

    // ---- S^T = phi * theta^T  ([64 keys] x [32 q]), bf16x3, log2 domain ----
    f32x4 s[4][2];
#pragma unroll
    for (int mt = 0; mt < 4; ++mt)
#pragma unroll
      for (int nt = 0; nt < 2; ++nt) s[mt][nt] = fzero4();

    __builtin_amdgcn_s_setprio(1);
#pragma unroll
    for (int mt = 0; mt < 4; ++mt) {
      const int row = mt * 16 + lrow;
      const int swz = (row & 7) << 4;
#pragma unroll
      for (int kk = 0; kk < 2; ++kk) {
        const int byte = row * 128 + ((kk * 64 + lhi * 16) ^ swz);
        const bf16x8 aH = *(const bf16x8*)(sKH + byte);
        const bf16x8 aL = *(const bf16x8*)(sKL + byte);
#pragma unroll
        for (int nt = 0; nt < 2; ++nt) {
          s[mt][nt] = mfma16(aH, qh[nt][kk],  s[mt][nt]);
          s[mt][nt] = mfma16(aH, qlv[nt][kk], s[mt][nt]);
          s[mt][nt] = mfma16(aL, qh[nt][kk],  s[mt][nt]);
        }
      }
    }
    __builtin_amdgcn_s_setprio(0);

    // ---- online softmax (exp2 domain); defer O-rescale when no new max ----
    float mx[2], a2[2];
#pragma unroll
    for (int nt = 0; nt < 2; ++nt) {
      float m1 = fmaxf(fmaxf(s[0][nt][0], s[0][nt][1]), fmaxf(s[0][nt][2], s[0][nt][3]));
      float m2 = fmaxf(fmaxf(s[1][nt][0], s[1][nt][1]), fmaxf(s[1][nt][2], s[1][nt][3]));
      float m3 = fmaxf(fmaxf(s[2][nt][0], s[2][nt][1]), fmaxf(s[2][nt][2], s[2][nt][3]));
      float m4 = fmaxf(fmaxf(s[3][nt][0], s[3][nt][1]), fmaxf(s[3][nt][2], s[3][nt][3]));
      float m = fmaxf(fmaxf(m1, m2), fmaxf(m3, m4));
      m = fmaxf(m, __shfl_xor(m, 16));
      m = fmaxf(m, __shfl_xor(m, 32));
      mx[nt] = m;
    }
    const bool up = !__all((mx[0] <= m_run[0]) && (mx[1] <= m_run[1]));
#pragma unroll
    for (int nt = 0; nt < 2; ++nt) {
      const float mnew  = up ? fmaxf(m_run[nt], mx[nt]) : m_run[nt];
      const float alpha = up ? exp2f(m_run[nt] - mnew) : 1.f;
      float lsum = 0.f;
#pragma unroll
      for (int mt = 0; mt < 4; ++mt)
#pragma unroll
        for (int r = 0; r < 4; ++r) {
          const float p = exp2f(s[mt][nt][r] - mnew);
          s[mt][nt][r] = p;
          lsum += p;
        }
      lsum += __shfl_xor(lsum, 16);
      lsum += __shfl_xor(lsum, 32);
      l_run[nt] = l_run[nt] * alpha + lsum;
      m_run[nt] = mnew;
      a2[nt] = alpha;
    }

    if (up) {
#pragma unroll
      for (int qt2 = 0; qt2 < 2; ++qt2) {
#pragma unroll
        for (int r = 0; r < 4; ++r) {
          const float av = __shfl(a2[qt2], lhi * 4 + r);
#pragma unroll
          for (int ct = 0; ct < 4; ++ct) oacc[qt2][ct][r] *= av;
        }
      }
    }

    // ---- pack P (bf16) into per-wave LDS [32 q][128B], XOR-swizzled ----
#pragma unroll
    for (int mt = 0; mt < 4; ++mt)
#pragma unroll
      for (int nt = 0; nt < 2; ++nt) {
        union { bf16_t h[4]; uint32_t u[2]; } pk;
#pragma unroll
        for (int r = 0; r < 4; ++r) pk.h[r] = (bf16_t)s[mt][nt][r];
        const int q    = nt * 16 + lrow;
        const int mloc = mt * 16 + lhi * 4;
        const int byte = q * 128 + ((mloc * 2) ^ ((q & 7) << 4));
        *(uint2*)(Pw + byte) = make_uint2(pk.u[0], pk.u[1]);
      }

    if (more) writeV(cur ^ 1, vnext);   // hidden under softmax/pack

    // ---- PV: O[q][c] += P[q][m] * V[m][c] ----
    const char* const sVc = sV[cur];
    bf16x8 bV[2][4];
#pragma unroll
    for (int ct = 0; ct < 4; ++ct) {
      const int row = ct * 16 + lrow;
      const int swz = (row & 7) << 4;
#pragma unroll
      for (int kk = 0; kk < 2; ++kk)
        bV[kk][ct] = *(const bf16x8*)(sVc + row * 128 + ((kk * 64 + lhi * 16) ^ swz));
    }
    __builtin_amdgcn_s_setprio(1);
#pragma unroll
    for (int qt2 = 0; qt2 < 2; ++qt2) {
      const int q = qt2 * 16 + lrow;
#pragma unroll
      for (int kk = 0; kk < 2; ++kk) {
        const bf16x8 pfrag =
            *(const bf16x8*)(Pw + q * 128 + ((kk * 64 + lhi * 16) ^ ((q & 7) << 4)));
#pragma unroll
        for (int ct = 0; ct < 4; ++ct)
          oacc[qt2][ct] = mfma16(pfrag, bV[kk][ct], oacc[qt2][ct]);
      }
    }
    __builtin_amdgcn_s_setprio(0);

    if (more) __syncthreads();
  }

  // ---- epilogue: unnormalized partial O (f16) + (m, l) ----
  f16_t* const Ob = Opart + ((size_t)(b * KSPL + ks) * NPIX) * 64;
#pragma unroll
  for (int qt2 = 0; qt2 < 2; ++qt2)
#pragma unroll
    for (int ct = 0; ct < 4; ++ct)
#pragma unroll
      for (int r = 0; r < 4; ++r) {
        const int q = q0 + qt2 * 16 + lhi * 4 + r;
        const int c = ct * 16 + lrow;
        Ob[(size_t)q * 64 + c] = (f16_t)oacc[qt2][ct][r];
      }
  if (lhi < 2) {
    const int q = q0 + lhi * 16 + lrow;
    const size_t base = ((size_t)(b * KSPL + ks) * NPIX + q) * 2;
    mlbuf[base]     = m_run[lhi];
    mlbuf[base + 1] = l_run[lhi];
  }
}

// ========================= stage 3: merge + wout + BN =======================
__global__ __launch_bounds__(256) void merge_out(
    const f16_t* __restrict__ Opart, const float* __restrict__ mlbuf,
    const float* __restrict__ ww,  const float* __restrict__ wb,
    const float* __restrict__ wg,  const float* __restrict__ wbt,
    const float* __restrict__ wm,  const float* __restrict__ wvv,
    float* __restrict__ out)
{
  __shared__ float wlds[128][64];
  __shared__ float bfw[128];
  __shared__ float mrg[32][68];

  const int tid = threadIdx.x;
  const int b   = blockIdx.y;
  const int n0  = blockIdx.x * 32;

  for (int idx = tid; idx < 128 * 64; idx += 256) {
    const int o = idx >> 6, c = idx & 63;
    const float sc = wg[o] * rsqrtf(wvv[o] + EPS);
    wlds[o][c] = ww[o * 64 + c] * sc;
    if (c == 0) bfw[o] = wb[o] * sc + wbt[o] - wm[o] * sc;
  }

  {
    const int px = tid & 31;
    const int cg = tid >> 5;
    const int q  = n0 + px;
    float mk[KSPL], lk[KSPL];
#pragma unroll
    for (int ks = 0; ks < KSPL; ++ks) {
      const size_t base = ((size_t)(b * KSPL + ks) * NPIX + q) * 2;
      mk[ks] = mlbuf[base];
      lk[ks] = mlbuf[base + 1];
    }
    float M = mk[0];
#pragma unroll
    for (int ks = 1; ks < KSPL; ++ks) M = fmaxf(M, mk[ks]);
    float al[KSPL]; float den = 0.f;
#pragma unroll
    for (int ks = 0; ks < KSPL; ++ks) { al[ks] = exp2f(mk[ks] - M); den += al[ks] * lk[ks]; }
    const float inv = 1.f / den;
#pragma unroll
    for (int ks = 0; ks < KSPL; ++ks) al[ks] *= inv;

    float r[8];
#pragma unroll
    for (int j = 0; j < 8; ++j) r[j] = 0.f;
#pragma unroll
    for (int ks = 0; ks < KSPL; ++ks) {
      const f16x8 p = *(const f16x8*)(Opart +
          ((size_t)(b * KSPL + ks) * NPIX + q) * 64 + cg * 8);
#pragma unroll
      for (int j = 0; j < 8; ++j) r[j] += (float)p[j] * al[ks];
    }
#pragma unroll
    for (int j = 0; j < 8; ++j) mrg[px][cg * 8 + j] = r[j];
  }
  __syncthreads();

  const int px = tid & 31;
  const int oh = tid >> 5;
  float acc[16];
#pragma unroll
  for (int j = 0; j < 16; ++j) acc[j] = 0.f;

#pragma unroll 4
  for (int c0 = 0; c0 < 64; c0 += 4) {
    const f32x4 m4 = *(const f32x4*)&mrg[px][c0];
#pragma unroll
    for (int j = 0; j < 16; ++j) {
      const f32x4 w4 = *(const f32x4*)&wlds[oh * 16 + j][c0];
      acc[j] += w4[0] * m4[0] + w4[1] * m4[1] + w4[2] * m4[2] + w4[3] * m4[3];
    }
  }
#pragma unroll
  for (int j = 0; j < 16; ++j) {
    const int o = oh * 16 + j;
    out[((size_t)b * 256 + o) * NPIX + n0 + px] = acc[j] + bfw[o];
  }
}

// ============================== launcher ====================================
extern "C" void kernel_launch(void* const* d_in, const int* in_sizes, int n_in,
                              void* d_out, int out_size, void* d_ws, size_t ws_size,
                              hipStream_t stream) {
  (void)in_sizes; (void)n_in; (void)out_size; (void)ws_size;
  const float* x1  = (const float*)d_in[0];
  const float* x2  = (const float*)d_in[1];
  const float* tw  = (const float*)d_in[2];
  const float* tb  = (const float*)d_in[3];
  const float* tg  = (const float*)d_in[4];
  const float* tbt = (const float*)d_in[5];
  const float* tm  = (const float*)d_in[6];
  const float* tv  = (const float*)d_in[7];
  const float* pw  = (const float*)d_in[8];
  const float* pb  = (const float*)d_in[9];
  const float* pg  = (const float*)d_in[10];
  const float* pbt = (const float*)d_in[11];
  const float* pm  = (const float*)d_in[12];
  const float* pv  = (const float*)d_in[13];
  const float* gw  = (const float*)d_in[14];
  const float* gb  = (const float*)d_in[15];
  const float* gg  = (const float*)d_in[16];
  const float* gbt = (const float*)d_in[17];
  const float* gmn = (const float*)d_in[18];
  const float* gv  = (const float*)d_in[19];
  const float* ww  = (const float*)d_in[20];
  const float* wb  = (const float*)d_in[21];
  const float* wg  = (const float*)d_in[22];
  const float* wbt = (const float*)d_in[23];
  const float* wm  = (const float*)d_in[24];
  const float* wv  = (const float*)d_in[25];

  float* out = (float*)d_out;
  char*  ws  = (char*)d_ws;
  bf16_t* thetaT_h = (bf16_t*)(ws);
  bf16_t* thetaT_l = (bf16_t*)(ws + (size_t)(2)  * 1048576);
  bf16_t* phiT_h   = (bf16_t*)(ws + (size_t)(4)  * 1048576);
  bf16_t* phiT_l   = (bf16_t*)(ws + (size_t)(6)  * 1048576);
  bf16_t* g_cm     = (bf16_t*)(ws + (size_t)(8)  * 1048576);
  f16_t*  Opart    = (f16_t*) (ws + (size_t)(10) * 1048576);
  float*  mlbuf    = (float*) (ws + (size_t)(26) * 1048576);

  dim3 gp(128, 4);
  proj_theta<<<gp, 256, 0, stream>>>(x1, tw, tb, tg, tbt, tm, tv,
                                     thetaT_h, thetaT_l, out);
  proj_phi<<<gp, 256, 0, stream>>>(x2, pw, pb, pg, pbt, pm, pv,
                                   phiT_h, phiT_l);
  proj_g<<<gp, 256, 0, stream>>>(x2, gw, gb, gg, gbt, gmn, gv, g_cm);
  flash_attn<<<512, 512, 0, stream>>>(thetaT_h, thetaT_l, phiT_h, phiT_l,
                                      g_cm, Opart, mlbuf);
  merge_out<<<gp, 256, 0, stream>>>(Opart, mlbuf, ww, wb, wg, wbt, wm, wv, out);
}

// Round 6
// 249.325 us; speedup vs baseline: 1.0018x; 1.0018x over previous
//
#include <hip/hip_runtime.h>
#include <stdint.h>
#include <stddef.h>

#define EPS   1e-5f
#define CINCH 128
#define CI    64
#define NPIX  4096
#define KSPL  8
#define LOG2E 1.44269504088896340736f

typedef __bf16 bf16_t;
typedef _Float16 f16_t;
typedef bf16_t bf16x8 __attribute__((ext_vector_type(8)));
typedef f16_t  f16x8  __attribute__((ext_vector_type(8)));
typedef float  f32x4  __attribute__((ext_vector_type(4)));

typedef __attribute__((address_space(3))) unsigned int lds_u32;
typedef __attribute__((address_space(1))) const unsigned int glb_u32;

__device__ __forceinline__ f32x4 mfma16(bf16x8 a, bf16x8 b, f32x4 c) {
  return __builtin_amdgcn_mfma_f32_16x16x32_bf16(a, b, c, 0, 0, 0);
}
__device__ __forceinline__ f32x4 fzero4() {
  f32x4 z = {0.f, 0.f, 0.f, 0.f};
  return z;
}
__device__ __forceinline__ void gload16(const void* g, void* l) {
  __builtin_amdgcn_global_load_lds((glb_u32*)g, (lds_u32*)l, 16, 0, 0);
}

// ---------------------------------------------------------------------------
// Workspace (MiB offsets):
//   thetaT_h [B][N][64] bf16 (x LOG2E)   0
//   thetaT_l [B][N][64] bf16 (x LOG2E)   2
//   phiT_h   [B][N][64] bf16 swizzled    4
//   phiT_l   [B][N][64] bf16 swizzled    6
//   g_cm     [B][64][N] bf16 plain       8
//   Opart    [B][8][N][64] f16          10   (16 MiB)
//   ml       [B][8][N][2]  f32          26   (1 MiB)
// phi global swizzle: within each 128B key-row, byte = (c*2) ^ ((key&7)<<4)
// V LDS swizzle: sV[c][x] = g_cm[c][x ^ ((c&7)<<4)] (involution, staged by
// inverse-swizzling the GLOBAL source; LDS dest stays linear for gload_lds).
// ---------------------------------------------------------------------------

// ===================== stage 1a: theta projection + x1 concat ===============
__global__ __launch_bounds__(256) void proj_theta(
    const float* __restrict__ x1,
    const float* __restrict__ w,  const float* __restrict__ bb,
    const float* __restrict__ gm, const float* __restrict__ bt,
    const float* __restrict__ mn, const float* __restrict__ vr,
    bf16_t* __restrict__ thetaT_h, bf16_t* __restrict__ thetaT_l,
    float* __restrict__ out)
{
  __shared__ float wT[CINCH][CI];                       // 32 KiB
  __shared__ float bfold[CI];
  __shared__ __align__(16) char ubuf[CINCH * 32 * 4];   // 16 KiB: xs / tileF
  float (*xs)[32]    = (float(*)[32])ubuf;
  float (*tileF)[68] = (float(*)[68])ubuf;

  const int tid = threadIdx.x;
  const int b   = blockIdx.y;
  const int n0  = blockIdx.x * 32;

  for (int idx = tid; idx < CI * CINCH; idx += 256) {
    const int o = idx & 63, c = idx >> 6;
    const float sc = gm[o] * rsqrtf(vr[o] + EPS);
    wT[c][o] = w[o * CINCH + c] * sc * LOG2E;
    if (c == 0) bfold[o] = (bb[o] * sc + bt[o] - mn[o] * sc) * LOG2E;
  }

  {
    const float* xsrc = x1 + (size_t)b * CINCH * NPIX + n0;
    float* osrc = out + ((size_t)b * 256 + 128) * NPIX + n0;
#pragma unroll
    for (int i = 0; i < 4; ++i) {
      const int idx = i * 256 + tid;
      const int c = idx >> 3, p = idx & 7;
      const f32x4 v = *(const f32x4*)(xsrc + (size_t)c * NPIX + p * 4);
      *(f32x4*)&xs[c][p * 4] = v;
      *(f32x4*)(osrc + (size_t)c * NPIX + p * 4) = v;
    }
  }
  __syncthreads();

  const int px = tid & 31;
  const int og = tid >> 5;
  float acc[8];
#pragma unroll
  for (int j = 0; j < 8; ++j) acc[j] = 0.f;

#pragma unroll 4
  for (int c0 = 0; c0 < CINCH; c0 += 4) {
    float xv[4];
#pragma unroll
    for (int cc = 0; cc < 4; ++cc) xv[cc] = xs[c0 + cc][px];
#pragma unroll
    for (int cc = 0; cc < 4; ++cc) {
      const f32x4 w0 = *(const f32x4*)&wT[c0 + cc][og * 8];
      const f32x4 w1 = *(const f32x4*)&wT[c0 + cc][og * 8 + 4];
#pragma unroll
      for (int j = 0; j < 4; ++j) {
        acc[j]     += w0[j] * xv[cc];
        acc[j + 4] += w1[j] * xv[cc];
      }
    }
  }
  __syncthreads();
#pragma unroll
  for (int j = 0; j < 8; ++j) tileF[px][og * 8 + j] = acc[j] + bfold[og * 8 + j];
  __syncthreads();

  {
    const int px2 = tid >> 3, ogs = tid & 7;
    bf16x8 hv, lv;
#pragma unroll
    for (int j = 0; j < 8; ++j) {
      const float v = tileF[px2][ogs * 8 + j];
      const bf16_t h = (bf16_t)v;
      hv[j] = h;
      lv[j] = (bf16_t)(v - (float)h);
    }
    const size_t base = ((size_t)b * NPIX + n0 + px2) * CI + ogs * 8;
    *(bf16x8*)(thetaT_h + base) = hv;
    *(bf16x8*)(thetaT_l + base) = lv;
  }
}

// ===================== stage 1b: phi projection (swizzled h/l) ==============
__global__ __launch_bounds__(256) void proj_phi(
    const float* __restrict__ x2,
    const float* __restrict__ w,  const float* __restrict__ bb,
    const float* __restrict__ gm, const float* __restrict__ bt,
    const float* __restrict__ mn, const float* __restrict__ vr,
    bf16_t* __restrict__ phiT_h, bf16_t* __restrict__ phiT_l)
{
  __shared__ float wT[CINCH][CI];
  __shared__ float bfold[CI];
  __shared__ __align__(16) char ubuf[CINCH * 32 * 4];
  float (*xs)[32]    = (float(*)[32])ubuf;
  float (*tileF)[68] = (float(*)[68])ubuf;

  const int tid = threadIdx.x;
  const int b   = blockIdx.y;
  const int n0  = blockIdx.x * 32;

  for (int idx = tid; idx < CI * CINCH; idx += 256) {
    const int o = idx & 63, c = idx >> 6;
    const float sc = gm[o] * rsqrtf(vr[o] + EPS);
    wT[c][o] = w[o * CINCH + c] * sc;
    if (c == 0) bfold[o] = bb[o] * sc + bt[o] - mn[o] * sc;
  }
  {
    const float* xsrc = x2 + (size_t)b * CINCH * NPIX + n0;
#pragma unroll
    for (int i = 0; i < 4; ++i) {
      const int idx = i * 256 + tid;
      const int c = idx >> 3, p = idx & 7;
      *(f32x4*)&xs[c][p * 4] = *(const f32x4*)(xsrc + (size_t)c * NPIX + p * 4);
    }
  }
  __syncthreads();

  const int px = tid & 31;
  const int og = tid >> 5;
  float acc[8];
#pragma unroll
  for (int j = 0; j < 8; ++j) acc[j] = 0.f;

#pragma unroll 4
  for (int c0 = 0; c0 < CINCH; c0 += 4) {
    float xv[4];
#pragma unroll
    for (int cc = 0; cc < 4; ++cc) xv[cc] = xs[c0 + cc][px];
#pragma unroll
    for (int cc = 0; cc < 4; ++cc) {
      const f32x4 w0 = *(const f32x4*)&wT[c0 + cc][og * 8];
      const f32x4 w1 = *(const f32x4*)&wT[c0 + cc][og * 8 + 4];
#pragma unroll
      for (int j = 0; j < 4; ++j) {
        acc[j]     += w0[j] * xv[cc];
        acc[j + 4] += w1[j] * xv[cc];
      }
    }
  }
  __syncthreads();
#pragma unroll
  for (int j = 0; j < 8; ++j) tileF[px][og * 8 + j] = acc[j] + bfold[og * 8 + j];
  __syncthreads();

  {
    const int px2 = tid >> 3, ogs = tid & 7;
    const int n = n0 + px2;
    bf16x8 hv, lv;
#pragma unroll
    for (int j = 0; j < 8; ++j) {
      const float v = tileF[px2][ogs * 8 + j];
      const bf16_t h = (bf16_t)v;
      hv[j] = h;
      lv[j] = (bf16_t)(v - (float)h);
    }
    const size_t rowb = ((size_t)b * NPIX + n) * 128;
    const int byte = (ogs * 16) ^ ((n & 7) << 4);
    *(bf16x8*)((char*)phiT_h + rowb + byte) = hv;
    *(bf16x8*)((char*)phiT_l + rowb + byte) = lv;
  }
}

// ===================== stage 1c: g projection (plain [c][m]) ================
__global__ __launch_bounds__(256) void proj_g(
    const float* __restrict__ x2,
    const float* __restrict__ w,  const float* __restrict__ bb,
    const float* __restrict__ gm, const float* __restrict__ bt,
    const float* __restrict__ mn, const float* __restrict__ vr,
    bf16_t* __restrict__ g_cm)
{
  __shared__ float wT[CINCH][CI];
  __shared__ float bfold[CI];
  __shared__ __align__(16) char ubuf[CINCH * 32 * 4];
  float (*xs)[32] = (float(*)[32])ubuf;
  float (*gT)[33] = (float(*)[33])ubuf;

  const int tid = threadIdx.x;
  const int b   = blockIdx.y;
  const int n0  = blockIdx.x * 32;

  for (int idx = tid; idx < CI * CINCH; idx += 256) {
    const int o = idx & 63, c = idx >> 6;
    const float sc = gm[o] * rsqrtf(vr[o] + EPS);
    wT[c][o] = w[o * CINCH + c] * sc;
    if (c == 0) bfold[o] = bb[o] * sc + bt[o] - mn[o] * sc;
  }
  {
    const float* xsrc = x2 + (size_t)b * CINCH * NPIX + n0;
#pragma unroll
    for (int i = 0; i < 4; ++i) {
      const int idx = i * 256 + tid;
      const int c = idx >> 3, p = idx & 7;
      *(f32x4*)&xs[c][p * 4] = *(const f32x4*)(xsrc + (size_t)c * NPIX + p * 4);
    }
  }
  __syncthreads();

  const int px = tid & 31;
  const int og = tid >> 5;
  float acc[8];
#pragma unroll
  for (int j = 0; j < 8; ++j) acc[j] = 0.f;

#pragma unroll 4
  for (int c0 = 0; c0 < CINCH; c0 += 4) {
    float xv[4];
#pragma unroll
    for (int cc = 0; cc < 4; ++cc) xv[cc] = xs[c0 + cc][px];
#pragma unroll
    for (int cc = 0; cc < 4; ++cc) {
      const f32x4 w0 = *(const f32x4*)&wT[c0 + cc][og * 8];
      const f32x4 w1 = *(const f32x4*)&wT[c0 + cc][og * 8 + 4];
#pragma unroll
      for (int j = 0; j < 4; ++j) {
        acc[j]     += w0[j] * xv[cc];
        acc[j + 4] += w1[j] * xv[cc];
      }
    }
  }
  __syncthreads();
#pragma unroll
  for (int j = 0; j < 8; ++j) gT[og * 8 + j][px] = acc[j] + bfold[og * 8 + j];
  __syncthreads();

  {
    const int c = tid & 63, mgp = tid >> 6;
    bf16x8 gv;
#pragma unroll
    for (int j = 0; j < 8; ++j) gv[j] = (bf16_t)gT[c][mgp * 8 + j];
    *(bf16x8*)(g_cm + ((size_t)b * CI + c) * NPIX + n0 + mgp * 8) = gv;
  }
}

// ========================= stage 2: flash attention =========================
// Grid: 512 = B(4) x qt(16) x ks(8). Block: 512 (8 waves x 32 q). KBLK=64.
// Counted-vmcnt pipeline: stage(t+1) issued after b1; vmcnt(3) keeps the 3
// newest (t+1) loads in flight across b2; compute(t). No full drains in loop.
__global__ __launch_bounds__(512, 4) void flash_attn(
    const bf16_t* __restrict__ thetaT_h, const bf16_t* __restrict__ thetaT_l,
    const bf16_t* __restrict__ phiT_h,   const bf16_t* __restrict__ phiT_l,
    const bf16_t* __restrict__ g_cm,
    f16_t* __restrict__ Opart, float* __restrict__ mlbuf)
{
  __shared__ __attribute__((aligned(16))) char sK[2][16384];  // [H 8K | L 8K]
  __shared__ __attribute__((aligned(16))) char sV[2][8192];   // [c][128B] swz
  __shared__ __attribute__((aligned(16))) char sP[8][4096];   // per-wave

  const int tid  = threadIdx.x;
  const int lane = tid & 63;
  const int wid  = tid >> 6;
  const int lrow = lane & 15;
  const int lhi  = lane >> 4;

  const int wg = blockIdx.x;
  const int b  = wg >> 7;
  const int rr = wg & 127;
  const int qt = rr >> 3;
  const int ks = rr & 7;
  const int q0 = qt * 256 + wid * 32;
  const int tg0 = ks * 8;                 // 8 tiles of 64 keys

  const char* const srcPHb = (const char*)phiT_h + ((size_t)b * NPIX) * 128;
  const char* const srcPLb = (const char*)phiT_l + ((size_t)b * NPIX) * 128;
  const char* const srcVb  = (const char*)g_cm + (size_t)b * CI * NPIX * 2;

  // V staging: thread -> row c = tid>>3, 16B part p = tid&7; inverse-swizzled
  // global source so linear LDS dest holds sV[c][x] = g[c][x ^ ((c&7)<<4)].
  const int vc = tid >> 3, vp = tid & 7;
  const size_t vsrcoff = (size_t)vc * (NPIX * 2) + ((vp * 16) ^ ((vc & 7) << 4));

  auto stage = [&](int buf, int tg) {
    const size_t rb = (size_t)tg * 8192;
    gload16(srcPHb + rb + tid * 16, sK[buf] + tid * 16);
    gload16(srcPLb + rb + tid * 16, sK[buf] + 8192 + tid * 16);
    gload16(srcVb + vsrcoff + (size_t)tg * 128, sV[buf] + tid * 16);
  };

  stage(0, tg0);

  // Q fragments (theta pre-scaled by LOG2E), h & l splits
  bf16x8 qh[2][2], qlv[2][2];
  {
    const bf16_t* qbh = thetaT_h + ((size_t)b * NPIX + q0 + lrow) * CI + lhi * 8;
    const bf16_t* qbl = thetaT_l + ((size_t)b * NPIX + q0 + lrow) * CI + lhi * 8;
#pragma unroll
    for (int nt = 0; nt < 2; ++nt)
#pragma unroll
      for (int kk = 0; kk < 2; ++kk) {
        qh[nt][kk]  = *(const bf16x8*)(qbh + nt * 16 * CI + kk * 32);
        qlv[nt][kk] = *(const bf16x8*)(qbl + nt * 16 * CI + kk * 32);
      }
  }

  f32x4 oacc[2][4];
#pragma unroll
  for (int a = 0; a < 2; ++a)
#pragma unroll
    for (int c = 0; c < 4; ++c) oacc[a][c] = fzero4();

  float m_run[2] = {-1e30f, -1e30f};
  float l_run[2] = {0.f, 0.f};

  char* const Pw = sP[wid];

  __syncthreads();   // prologue: full drain (stage(0) + Q) + barrier

  for (int t = 0; t < 8; ++t) {
    const int cur = t & 1;

    if (t) {  // b1: close tile t-1's reads of buf cur^1 before DMA reuse
      asm volatile("s_waitcnt lgkmcnt(0)" ::: "memory");
      __builtin_amdgcn_s_barrier();
    }
    if (t < 7) {
      stage(cur ^ 1, tg0 + t + 1);
      asm volatile("s_waitcnt vmcnt(3)" ::: "memory");  // stage(t) landed
    } else {
      asm volatile("s_waitcnt vmcnt(0)" ::: "memory");
    }
    __builtin_amdgcn_s_barrier();          // b2: ALL waves' stage(t) landed
    __builtin_amdgcn_sched_barrier(0);

    const char* const sKH = sK[cur];
    const char* const sKL = sK[cur] + 8192;
    const char* const sVc = sV[cur];

    // ---- S^T = phi * theta^T  ([64 keys] x [32 q]), bf16x3, log2 domain ----
    f32x4 s[4][2];
#pragma unroll
    for (int mt = 0; mt < 4; ++mt)
#pragma unroll
      for (int nt = 0; nt < 2; ++nt) s[mt][nt] = fzero4();

    __builtin_amdgcn_s_setprio(1);
#pragma unroll
    for (int mt = 0; mt < 4; ++mt) {
      const int row = mt * 16 + lrow;
      const int swz = (row & 7) << 4;
#pragma unroll
      for (int kk = 0; kk < 2; ++kk) {
        const int byte = row * 128 + ((kk * 64 + lhi * 16) ^ swz);
        const bf16x8 aH = *(const bf16x8*)(sKH + byte);
        const bf16x8 aL = *(const bf16x8*)(sKL + byte);
#pragma unroll
        for (int nt = 0; nt < 2; ++nt) {
          s[mt][nt] = mfma16(aH, qh[nt][kk],  s[mt][nt]);
          s[mt][nt] = mfma16(aH, qlv[nt][kk], s[mt][nt]);
          s[mt][nt] = mfma16(aL, qh[nt][kk],  s[mt][nt]);
        }
      }
    }
    __builtin_amdgcn_s_setprio(0);

    // ---- online softmax (exp2 domain); defer O-rescale (THR=5) ----
    float mx[2], a2[2];
#pragma unroll
    for (int nt = 0; nt < 2; ++nt) {
      float m1 = fmaxf(fmaxf(s[0][nt][0], s[0][nt][1]), fmaxf(s[0][nt][2], s[0][nt][3]));
      float m2 = fmaxf(fmaxf(s[1][nt][0], s[1][nt][1]), fmaxf(s[1][nt][2], s[1][nt][3]));
      float m3 = fmaxf(fmaxf(s[2][nt][0], s[2][nt][1]), fmaxf(s[2][nt][2], s[2][nt][3]));
      float m4 = fmaxf(fmaxf(s[3][nt][0], s[3][nt][1]), fmaxf(s[3][nt][2], s[3][nt][3]));
      float m = fmaxf(fmaxf(m1, m2), fmaxf(m3, m4));
      m = fmaxf(m, __shfl_xor(m, 16));
      m = fmaxf(m, __shfl_xor(m, 32));
      mx[nt] = m;
    }
    const bool up = !__all((mx[0] <= m_run[0] + 5.f) && (mx[1] <= m_run[1] + 5.f));
#pragma unroll
    for (int nt = 0; nt < 2; ++nt) {
      const float mnew  = up ? fmaxf(m_run[nt], mx[nt]) : m_run[nt];
      const float alpha = up ? exp2f(m_run[nt] - mnew) : 1.f;
      float lsum = 0.f;
#pragma unroll
      for (int mt = 0; mt < 4; ++mt)
#pragma unroll
        for (int r = 0; r < 4; ++r) {
          const float p = exp2f(s[mt][nt][r] - mnew);
          s[mt][nt][r] = p;
          lsum += p;
        }
      lsum += __shfl_xor(lsum, 16);
      lsum += __shfl_xor(lsum, 32);
      l_run[nt] = l_run[nt] * alpha + lsum;
      m_run[nt] = mnew;
      a2[nt] = alpha;
    }

    if (up) {
#pragma unroll
      for (int qt2 = 0; qt2 < 2; ++qt2) {
#pragma unroll
        for (int r = 0; r < 4; ++r) {
          const float av = __shfl(a2[qt2], lhi * 4 + r);
#pragma unroll
          for (int ct = 0; ct < 4; ++ct) oacc[qt2][ct][r] *= av;
        }
      }
    }

    // ---- pack P (bf16) into per-wave LDS [32 q][128B], XOR-swizzled ----
#pragma unroll
    for (int mt = 0; mt < 4; ++mt)
#pragma unroll
      for (int nt = 0; nt < 2; ++nt) {
        union { bf16_t h[4]; uint32_t u[2]; } pk;
#pragma unroll
        for (int r = 0; r < 4; ++r) pk.h[r] = (bf16_t)s[mt][nt][r];
        const int q    = nt * 16 + lrow;
        const int mloc = mt * 16 + lhi * 4;
        const int byte = q * 128 + ((mloc * 2) ^ ((q & 7) << 4));
        *(uint2*)(Pw + byte) = make_uint2(pk.u[0], pk.u[1]);
      }

    // ---- PV: O[q][c] += P[q][m] * V[m][c] ----
    bf16x8 bV[2][4];
#pragma unroll
    for (int ct = 0; ct < 4; ++ct) {
      const int row = ct * 16 + lrow;
      const int swz = (row & 7) << 4;
#pragma unroll
      for (int kk = 0; kk < 2; ++kk)
        bV[kk][ct] = *(const bf16x8*)(sVc + row * 128 + ((kk * 64 + lhi * 16) ^ swz));
    }
    __builtin_amdgcn_s_setprio(1);
#pragma unroll
    for (int qt2 = 0; qt2 < 2; ++qt2) {
      const int q = qt2 * 16 + lrow;
#pragma unroll
      for (int kk = 0; kk < 2; ++kk) {
        const bf16x8 pfrag =
            *(const bf16x8*)(Pw + q * 128 + ((kk * 64 + lhi * 16) ^ ((q & 7) << 4)));
#pragma unroll
        for (int ct = 0; ct < 4; ++ct)
          oacc[qt2][ct] = mfma16(pfrag, bV[kk][ct], oacc[qt2][ct]);
      }
    }
    __builtin_amdgcn_s_setprio(0);
  }

  // ---- epilogue: coalesced unnormalized partial O (f16) via LDS transpose --
  {
#pragma unroll
    for (int qt2 = 0; qt2 < 2; ++qt2)
#pragma unroll
      for (int ct = 0; ct < 4; ++ct)
#pragma unroll
        for (int r = 0; r < 4; ++r) {
          const int ql = qt2 * 16 + lhi * 4 + r;
          const int c  = ct * 16 + lrow;
          *(f16_t*)(Pw + (ql * 64 + c) * 2) = (f16_t)oacc[qt2][ct][r];
        }
    // per-wave buffer, same-wave readback (compiler inserts lgkmcnt)
    f16_t* const Ob = Opart + ((size_t)(b * KSPL + ks) * NPIX + q0) * 64;
#pragma unroll
    for (int i = 0; i < 4; ++i) {
      const int idx = i * 64 + lane;        // 256 chunks of 16B
      *(f16x8*)(Ob + idx * 8) = *(const f16x8*)(Pw + idx * 16);
    }
  }
  if (lhi < 2) {
    const int q = q0 + lhi * 16 + lrow;
    const size_t base = ((size_t)(b * KSPL + ks) * NPIX + q) * 2;
    mlbuf[base]     = m_run[lhi];
    mlbuf[base + 1] = l_run[lhi];
  }
}

// ========================= stage 3: merge + wout + BN =======================
__global__ __launch_bounds__(256) void merge_out(
    const f16_t* __restrict__ Opart, const float* __restrict__ mlbuf,
    const float* __restrict__ ww,  const float* __restrict__ wb,
    const float* __restrict__ wg,  const float* __restrict__ wbt,
    const float* __restrict__ wm,  const float* __restrict__ wvv,
    float* __restrict__ out)
{
  __shared__ float wlds[128][64];
  __shared__ float bfw[128];
  __shared__ float mrg[32][68];

  const int tid = threadIdx.x;
  const int b   = blockIdx.y;
  const int n0  = blockIdx.x * 32;

  for (int idx = tid; idx < 128 * 64; idx += 256) {
    const int o = idx >> 6, c = idx & 63;
    const float sc = wg[o] * rsqrtf(wvv[o] + EPS);
    wlds[o][c] = ww[o * 64 + c] * sc;
    if (c == 0) bfw[o] = wb[o] * sc + wbt[o] - wm[o] * sc;
  }

  {
    const int px = tid & 31;
    const int cg = tid >> 5;
    const int q  = n0 + px;
    float mk[KSPL], lk[KSPL];
#pragma unroll
    for (int ks = 0; ks < KSPL; ++ks) {
      const size_t base = ((size_t)(b * KSPL + ks) * NPIX + q) * 2;
      mk[ks] = mlbuf[base];
      lk[ks] = mlbuf[base + 1];
    }
    float M = mk[0];
#pragma unroll
    for (int ks = 1; ks < KSPL; ++ks) M = fmaxf(M, mk[ks]);
    float al[KSPL]; float den = 0.f;
#pragma unroll
    for (int ks = 0; ks < KSPL; ++ks) { al[ks] = exp2f(mk[ks] - M); den += al[ks] * lk[ks]; }
    const float inv = 1.f / den;
#pragma unroll
    for (int ks = 0; ks < KSPL; ++ks) al[ks] *= inv;

    float r[8];
#pragma unroll
    for (int j = 0; j < 8; ++j) r[j] = 0.f;
#pragma unroll
    for (int ks = 0; ks < KSPL; ++ks) {
      const f16x8 p = *(const f16x8*)(Opart +
          ((size_t)(b * KSPL + ks) * NPIX + q) * 64 + cg * 8);
#pragma unroll
      for (int j = 0; j < 8; ++j) r[j] += (float)p[j] * al[ks];
    }
#pragma unroll
    for (int j = 0; j < 8; ++j) mrg[px][cg * 8 + j] = r[j];
  }
  __syncthreads();

  const int px = tid & 31;
  const int oh = tid >> 5;
  float acc[16];
#pragma unroll
  for (int j = 0; j < 16; ++j) acc[j] = 0.f;

#pragma unroll 4
  for (int c0 = 0; c0 < 64; c0 += 4) {
    const f32x4 m4 = *(const f32x4*)&mrg[px][c0];
#pragma unroll
    for (int j = 0; j < 16; ++j) {
      const f32x4 w4 = *(const f32x4*)&wlds[oh * 16 + j][c0];
      acc[j] += w4[0] * m4[0] + w4[1] * m4[1] + w4[2] * m4[2] + w4[3] * m4[3];
    }
  }
#pragma unroll
  for (int j = 0; j < 16; ++j) {
    const int o = oh * 16 + j;
    out[((size_t)b * 256 + o) * NPIX + n0 + px] = acc[j] + bfw[o];
  }
}

// ============================== launcher ====================================
extern "C" void kernel_launch(void* const* d_in, const int* in_sizes, int n_in,
                              void* d_out, int out_size, void* d_ws, size_t ws_size,
                              hipStream_t stream) {
  (void)in_sizes; (void)n_in; (void)out_size; (void)ws_size;
  const float* x1  = (const float*)d_in[0];
  const float* x2  = (const float*)d_in[1];
  const float* tw  = (const float*)d_in[2];
  const float* tb  = (const float*)d_in[3];
  const float* tg  = (const float*)d_in[4];
  const float* tbt = (const float*)d_in[5];
  const float* tm  = (const float*)d_in[6];
  const float* tv  = (const float*)d_in[7];
  const float* pw  = (const float*)d_in[8];
  const float* pb  = (const float*)d_in[9];
  const float* pg  = (const float*)d_in[10];
  const float* pbt = (const float*)d_in[11];
  const float* pm  = (const float*)d_in[12];
  const float* pv  = (const float*)d_in[13];
  const float* gw  = (const float*)d_in[14];
  const float* gb  = (const float*)d_in[15];
  const float* gg  = (const float*)d_in[16];
  const float* gbt = (const float*)d_in[17];
  const float* gmn = (const float*)d_in[18];
  const float* gv  = (const float*)d_in[19];
  const float* ww  = (const float*)d_in[20];
  const float* wb  = (const float*)d_in[21];
  const float* wg  = (const float*)d_in[22];
  const float* wbt = (const float*)d_in[23];
  const float* wm  = (const float*)d_in[24];
  const float* wv  = (const float*)d_in[25];

  float* out = (float*)d_out;
  char*  ws  = (char*)d_ws;
  bf16_t* thetaT_h = (bf16_t*)(ws);
  bf16_t* thetaT_l = (bf16_t*)(ws + (size_t)(2)  * 1048576);
  bf16_t* phiT_h   = (bf16_t*)(ws + (size_t)(4)  * 1048576);
  bf16_t* phiT_l   = (bf16_t*)(ws + (size_t)(6)  * 1048576);
  bf16_t* g_cm     = (bf16_t*)(ws + (size_t)(8)  * 1048576);
  f16_t*  Opart    = (f16_t*) (ws + (size_t)(10) * 1048576);
  float*  mlbuf    = (float*) (ws + (size_t)(26) * 1048576);

  dim3 gp(128, 4);
  proj_theta<<<gp, 256, 0, stream>>>(x1, tw, tb, tg, tbt, tm, tv,
                                     thetaT_h, thetaT_l, out);
  proj_phi<<<gp, 256, 0, stream>>>(x2, pw, pb, pg, pbt, pm, pv,
                                   phiT_h, phiT_l);
  proj_g<<<gp, 256, 0, stream>>>(x2, gw, gb, gg, gbt, gmn, gv, g_cm);
  flash_attn<<<512, 512, 0, stream>>>(thetaT_h, thetaT_l, phiT_h, phiT_l,
                                      g_cm, Opart, mlbuf);
  merge_out<<<gp, 256, 0, stream>>>(Opart, mlbuf, ww, wb, wg, wbt, wm, wv, out);
}

// Round 9
// 226.574 us; speedup vs baseline: 1.1024x; 1.1004x over previous
//
#include <hip/hip_runtime.h>
#include <stdint.h>
#include <stddef.h>

#define EPS   1e-5f
#define CINCH 128
#define CI    64
#define NPIX  4096
#define KSPL  4
#define LOG2E 1.44269504088896340736f

typedef __bf16 bf16_t;
typedef _Float16 f16_t;
typedef bf16_t bf16x8 __attribute__((ext_vector_type(8)));
typedef f16_t  f16x8  __attribute__((ext_vector_type(8)));
typedef float  f32x4  __attribute__((ext_vector_type(4)));

typedef __attribute__((address_space(3))) unsigned int lds_u32;
typedef __attribute__((address_space(1))) const unsigned int glb_u32;

__device__ __forceinline__ f32x4 mfma16(bf16x8 a, bf16x8 b, f32x4 c) {
  return __builtin_amdgcn_mfma_f32_16x16x32_bf16(a, b, c, 0, 0, 0);
}
__device__ __forceinline__ f32x4 fzero4() {
  f32x4 z = {0.f, 0.f, 0.f, 0.f};
  return z;
}
__device__ __forceinline__ void gload16(const void* g, void* l) {
  __builtin_amdgcn_global_load_lds((glb_u32*)g, (lds_u32*)l, 16, 0, 0);
}

// ---------------------------------------------------------------------------
// Workspace (MiB offsets):
//   thetaT_h [B][N][64] bf16 (x LOG2E)   0
//   thetaT_l [B][N][64] bf16 (x LOG2E)   2
//   phiT_h   [B][N][64] bf16 swizzled    4
//   phiT_l   [B][N][64] bf16 swizzled    6
//   g_cm     [B][64][N] bf16 plain       8
//   Opart    [B][4][N][64] f16          10   (8 MiB)
//   ml       [B][4][N][2]  f32          18   (0.5 MiB)
// phi global swizzle: within each 128B key-row, byte = (c*2) ^ ((key&7)<<4)
// V LDS swizzle: sV[c][x] = g_cm[c][x ^ ((c&7)<<4)] via inverse-swizzled
// GLOBAL source (LDS dest linear for gload_lds).
// ---------------------------------------------------------------------------

// ============ stage 1: fused theta/phi/g projections + x1 concat ============
// grid (128,4), 256 thr, ~57 KB LDS -> 2 blocks/CU. Three phases share one
// weight tile and one x tile; x2 staged once for phi+g. Bias is folded into
// acc BEFORE each barrier (bf[] is overwritten by the next loadW after it).
__global__ __launch_bounds__(256) void proj_all(
    const float* __restrict__ x1, const float* __restrict__ x2,
    const float* __restrict__ tw, const float* __restrict__ tb,
    const float* __restrict__ tg, const float* __restrict__ tbt,
    const float* __restrict__ tm, const float* __restrict__ tv,
    const float* __restrict__ pw, const float* __restrict__ pb,
    const float* __restrict__ pg, const float* __restrict__ pbt,
    const float* __restrict__ pm, const float* __restrict__ pv,
    const float* __restrict__ gw, const float* __restrict__ gb,
    const float* __restrict__ gg, const float* __restrict__ gbt,
    const float* __restrict__ gmn, const float* __restrict__ gv,
    bf16_t* __restrict__ thetaT_h, bf16_t* __restrict__ thetaT_l,
    bf16_t* __restrict__ phiT_h,   bf16_t* __restrict__ phiT_l,
    bf16_t* __restrict__ g_cm,     float* __restrict__ out)
{
  __shared__ float wT[CINCH][CI];                      // 32 KiB, per-phase
  __shared__ float bf[CI];
  __shared__ float xs[CINCH][32];                      // 16 KiB x tile
  __shared__ __align__(16) char tbuf[32 * 68 * 4];     // 8.7 KiB transpose
  float (*tF)[68] = (float(*)[68])tbuf;
  float (*gT)[33] = (float(*)[33])tbuf;                // 64x33 fits

  const int tid = threadIdx.x;
  const int b   = blockIdx.y;
  const int n0  = blockIdx.x * 32;
  const int px  = tid & 31;
  const int og  = tid >> 5;

  auto loadW = [&](const float* w, const float* bb_, const float* gm_,
                   const float* bt_, const float* mn_, const float* vr_,
                   float mul) {
    for (int idx = tid; idx < CI * CINCH; idx += 256) {
      const int o = idx & 63, c = idx >> 6;
      const float sc = gm_[o] * rsqrtf(vr_[o] + EPS);
      wT[c][o] = w[o * CINCH + c] * sc * mul;
      if (c == 0) bf[o] = (bb_[o] * sc + bt_[o] - mn_[o] * sc) * mul;
    }
  };
  auto stageX = [&](const float* x) {
    const float* xsrc = x + (size_t)b * CINCH * NPIX + n0;
#pragma unroll
    for (int i = 0; i < 4; ++i) {
      const int idx = i * 256 + tid;
      const int c = idx >> 3, p = idx & 7;
      *(f32x4*)&xs[c][p * 4] = *(const f32x4*)(xsrc + (size_t)c * NPIX + p * 4);
    }
  };
  auto compute = [&](float* acc) {
#pragma unroll
    for (int j = 0; j < 8; ++j) acc[j] = 0.f;
#pragma unroll 4
    for (int c0 = 0; c0 < CINCH; c0 += 4) {
      float xv[4];
#pragma unroll
      for (int cc = 0; cc < 4; ++cc) xv[cc] = xs[c0 + cc][px];
#pragma unroll
      for (int cc = 0; cc < 4; ++cc) {
        const f32x4 w0 = *(const f32x4*)&wT[c0 + cc][og * 8];
        const f32x4 w1 = *(const f32x4*)&wT[c0 + cc][og * 8 + 4];
#pragma unroll
        for (int j = 0; j < 4; ++j) {
          acc[j]     += w0[j] * xv[cc];
          acc[j + 4] += w1[j] * xv[cc];
        }
      }
    }
    // fold bias NOW: bf[] is stable until the next loadW, which only runs
    // after the next barrier; reading it after that barrier would race.
#pragma unroll
    for (int j = 0; j < 8; ++j) acc[j] += bf[og * 8 + j];
  };

  float acc[8];

  // ---- phase theta ----
  loadW(tw, tb, tg, tbt, tm, tv, LOG2E);
  {  // stage x1 + fused concat copy (out channels [128,256) = x1)
    const float* xsrc = x1 + (size_t)b * CINCH * NPIX + n0;
    float* odst = out + ((size_t)b * 256 + 128) * NPIX + n0;
#pragma unroll
    for (int i = 0; i < 4; ++i) {
      const int idx = i * 256 + tid;
      const int c = idx >> 3, p = idx & 7;
      const f32x4 v = *(const f32x4*)(xsrc + (size_t)c * NPIX + p * 4);
      *(f32x4*)&xs[c][p * 4] = v;
      *(f32x4*)(odst + (size_t)c * NPIX + p * 4) = v;
    }
  }
  __syncthreads();                       // s0: wT/bf/xs ready
  compute(acc);                          // acc includes theta bias
  __syncthreads();                       // s1: all wT/bf/xs readers done
#pragma unroll
  for (int j = 0; j < 8; ++j) tF[px][og * 8 + j] = acc[j];
  loadW(pw, pb, pg, pbt, pm, pv, 1.f);   // overwrite wT/bf with phi
  stageX(x2);                            // overwrite xs with x2
  __syncthreads();                       // s2: tF/wT/bf/xs ready
  {  // store theta h/l (coalesced: 8 lanes per 128B row)
    const int px2 = tid >> 3, ogs = tid & 7;
    bf16x8 hv, lv;
#pragma unroll
    for (int j = 0; j < 8; ++j) {
      const float v = tF[px2][ogs * 8 + j];
      const bf16_t h = (bf16_t)v;
      hv[j] = h;
      lv[j] = (bf16_t)(v - (float)h);
    }
    const size_t base = ((size_t)b * NPIX + n0 + px2) * CI + ogs * 8;
    *(bf16x8*)(thetaT_h + base) = hv;
    *(bf16x8*)(thetaT_l + base) = lv;
  }

  // ---- phase phi ----
  compute(acc);                          // acc includes phi bias
  __syncthreads();                       // s3: tF readers + wT/bf readers done
#pragma unroll
  for (int j = 0; j < 8; ++j) tF[px][og * 8 + j] = acc[j];
  loadW(gw, gb, gg, gbt, gmn, gv, 1.f);  // overwrite wT/bf with g
  __syncthreads();                       // s4
  {  // store phi h/l, globally swizzled
    const int px2 = tid >> 3, ogs = tid & 7;
    const int n = n0 + px2;
    bf16x8 hv, lv;
#pragma unroll
    for (int j = 0; j < 8; ++j) {
      const float v = tF[px2][ogs * 8 + j];
      const bf16_t h = (bf16_t)v;
      hv[j] = h;
      lv[j] = (bf16_t)(v - (float)h);
    }
    const size_t rowb = ((size_t)b * NPIX + n) * 128;
    const int byte = (ogs * 16) ^ ((n & 7) << 4);
    *(bf16x8*)((char*)phiT_h + rowb + byte) = hv;
    *(bf16x8*)((char*)phiT_l + rowb + byte) = lv;
  }

  // ---- phase g ----
  compute(acc);                          // acc includes g bias
  __syncthreads();                       // s5: tF readers (phi store) done
#pragma unroll
  for (int j = 0; j < 8; ++j) gT[og * 8 + j][px] = acc[j];
  __syncthreads();                       // s6
  {  // store g plain [c][m], coalesced bf16x8
    const int c = tid & 63, mgp = tid >> 6;
    bf16x8 gv;
#pragma unroll
    for (int j = 0; j < 8; ++j) gv[j] = (bf16_t)gT[c][mgp * 8 + j];
    *(bf16x8*)(g_cm + ((size_t)b * CI + c) * NPIX + n0 + mgp * 8) = gv;
  }
}

// ========================= stage 2: flash attention =========================
// Grid: 512 = B(4) x qt(32) x ks(4). Block: 256 (4 waves x 32 q). KBLK=64.
// Round-2 proven structure: stage(next) before compute, one syncthreads/tile.
// LDS 64 KB -> 2 blocks/CU.
__global__ __launch_bounds__(256, 2) void flash_attn(
    const bf16_t* __restrict__ thetaT_h, const bf16_t* __restrict__ thetaT_l,
    const bf16_t* __restrict__ phiT_h,   const bf16_t* __restrict__ phiT_l,
    const bf16_t* __restrict__ g_cm,
    f16_t* __restrict__ Opart, float* __restrict__ mlbuf)
{
  __shared__ __attribute__((aligned(16))) char sT[2][24576];  // H|L|V per buf
  __shared__ __attribute__((aligned(16))) char sP[4][4096];   // per-wave

  const int tid  = threadIdx.x;
  const int lane = tid & 63;
  const int wid  = tid >> 6;
  const int lrow = lane & 15;
  const int lhi  = lane >> 4;

  const int wg = blockIdx.x;
  const int b  = wg >> 7;
  const int rr = wg & 127;
  const int qt = rr >> 2;
  const int ks = rr & 3;
  const int q0 = qt * 128 + wid * 32;
  const int t0 = ks * 16;                // 16 tiles of 64 keys

  const char* const srcPHb = (const char*)phiT_h + ((size_t)b * NPIX) * 128;
  const char* const srcPLb = (const char*)phiT_l + ((size_t)b * NPIX) * 128;
  const char* const srcVb  = (const char*)g_cm + (size_t)b * CI * NPIX * 2;

  auto stage = [&](int buf, int tile) {
    const size_t rb = (size_t)tile * 8192;
    char* const dst = sT[buf];
    gload16(srcPHb + rb + tid * 16,         dst + tid * 16);
    gload16(srcPHb + rb + (256 + tid) * 16, dst + (256 + tid) * 16);
    gload16(srcPLb + rb + tid * 16,         dst + 8192 + tid * 16);
    gload16(srcPLb + rb + (256 + tid) * 16, dst + 8192 + (256 + tid) * 16);
#pragma unroll
    for (int k = 0; k < 2; ++k) {   // V: inverse-swizzled global source
      const int c2 = k * 256 + tid;
      const int row = c2 >> 3, part = c2 & 7;
      gload16(srcVb + (size_t)row * (NPIX * 2) + tile * 128 +
                  ((part * 16) ^ ((row & 7) << 4)),
              dst + 16384 + c2 * 16);
    }
  };

  stage(0, t0);

  // Q fragments (theta pre-scaled by LOG2E), h & l splits
  bf16x8 qh[2][2], qlv[2][2];
  {
    const bf16_t* qbh = thetaT_h + ((size_t)b * NPIX + q0 + lrow) * CI + lhi * 8;
    const bf16_t* qbl = thetaT_l + ((size_t)b * NPIX + q0 + lrow) * CI + lhi * 8;
#pragma unroll
    for (int nt = 0; nt < 2; ++nt)
#pragma unroll
      for (int kk = 0; kk < 2; ++kk) {
        qh[nt][kk]  = *(const bf16x8*)(qbh + nt * 16 * CI + kk * 32);
        qlv[nt][kk] = *(const bf16x8*)(qbl + nt * 16 * CI + kk * 32);
      }
  }

  f32x4 oacc[2][4];
#pragma unroll
  for (int a = 0; a < 2; ++a)
#pragma unroll
    for (int c = 0; c < 4; ++c) oacc[a][c] = fzero4();

  float m_run[2] = {-1e30f, -1e30f};
  float l_run[2] = {0.f, 0.f};

  char* const Pw = sP[wid];

  __syncthreads();   // stage(0) drained (implicit vmcnt0) + barrier

  for (int tt = 0; tt < 16; ++tt) {
    const int cur = tt & 1;
    if (tt < 15) stage(cur ^ 1, t0 + tt + 1);   // prefetch next tile

    const char* const sKH = sT[cur];
    const char* const sKL = sT[cur] + 8192;
    const char* const sVc = sT[cur] + 16384;

    // ---- S^T = phi * theta^T ([64 keys] x [32 q]), bf16x3, log2 domain ----
    f32x4 s[4][2];
#pragma unroll
    for (int mt = 0; mt < 4; ++mt)
#pragma unroll
      for (int nt = 0; nt < 2; ++nt) s[mt][nt] = fzero4();

    __builtin_amdgcn_s_setprio(1);
#pragma unroll
    for (int mt = 0; mt < 4; ++mt) {
      const int row = mt * 16 + lrow;
      const int swz = (row & 7) << 4;
#pragma unroll
      for (int kk = 0; kk < 2; ++kk) {
        const int byte = row * 128 + ((kk * 64 + lhi * 16) ^ swz);
        const bf16x8 aH = *(const bf16x8*)(sKH + byte);
        const bf16x8 aL = *(const bf16x8*)(sKL + byte);
#pragma unroll
        for (int nt = 0; nt < 2; ++nt) {
          s[mt][nt] = mfma16(aH, qh[nt][kk],  s[mt][nt]);
          s[mt][nt] = mfma16(aH, qlv[nt][kk], s[mt][nt]);
          s[mt][nt] = mfma16(aL, qh[nt][kk],  s[mt][nt]);
        }
      }
    }
    __builtin_amdgcn_s_setprio(0);

    // ---- online softmax (exp2 domain); defer O-rescale (THR=5) ----
    float mx[2], a2[2];
#pragma unroll
    for (int nt = 0; nt < 2; ++nt) {
      float m1 = fmaxf(fmaxf(s[0][nt][0], s[0][nt][1]), fmaxf(s[0][nt][2], s[0][nt][3]));
      float m2 = fmaxf(fmaxf(s[1][nt][0], s[1][nt][1]), fmaxf(s[1][nt][2], s[1][nt][3]));
      float m3 = fmaxf(fmaxf(s[2][nt][0], s[2][nt][1]), fmaxf(s[2][nt][2], s[2][nt][3]));
      float m4 = fmaxf(fmaxf(s[3][nt][0], s[3][nt][1]), fmaxf(s[3][nt][2], s[3][nt][3]));
      float m = fmaxf(fmaxf(m1, m2), fmaxf(m3, m4));
      m = fmaxf(m, __shfl_xor(m, 16));
      m = fmaxf(m, __shfl_xor(m, 32));
      mx[nt] = m;
    }
    const bool up = !__all((mx[0] <= m_run[0] + 5.f) && (mx[1] <= m_run[1] + 5.f));
#pragma unroll
    for (int nt = 0; nt < 2; ++nt) {
      const float mnew  = up ? fmaxf(m_run[nt], mx[nt]) : m_run[nt];
      const float alpha = up ? exp2f(m_run[nt] - mnew) : 1.f;
      float lsum = 0.f;
#pragma unroll
      for (int mt = 0; mt < 4; ++mt)
#pragma unroll
        for (int r = 0; r < 4; ++r) {
          const float p = exp2f(s[mt][nt][r] - mnew);
          s[mt][nt][r] = p;
          lsum += p;
        }
      lsum += __shfl_xor(lsum, 16);
      lsum += __shfl_xor(lsum, 32);
      l_run[nt] = l_run[nt] * alpha + lsum;
      m_run[nt] = mnew;
      a2[nt] = alpha;
    }

    if (up) {
#pragma unroll
      for (int qt2 = 0; qt2 < 2; ++qt2) {
#pragma unroll
        for (int r = 0; r < 4; ++r) {
          const float av = __shfl(a2[qt2], lhi * 4 + r);
#pragma unroll
          for (int ct = 0; ct < 4; ++ct) oacc[qt2][ct][r] *= av;
        }
      }
    }

    // ---- pack P (bf16) into per-wave LDS [32 q][128B], XOR-swizzled ----
#pragma unroll
    for (int mt = 0; mt < 4; ++mt)
#pragma unroll
      for (int nt = 0; nt < 2; ++nt) {
        union { bf16_t h[4]; uint32_t u[2]; } pk;
#pragma unroll
        for (int r = 0; r < 4; ++r) pk.h[r] = (bf16_t)s[mt][nt][r];
        const int q    = nt * 16 + lrow;
        const int mloc = mt * 16 + lhi * 4;
        const int byte = q * 128 + ((mloc * 2) ^ ((q & 7) << 4));
        *(uint2*)(Pw + byte) = make_uint2(pk.u[0], pk.u[1]);
      }

    // ---- PV: O[q][c] += P[q][m] * V[m][c] ----
    bf16x8 bV[2][4];
#pragma unroll
    for (int ct = 0; ct < 4; ++ct) {
      const int row = ct * 16 + lrow;
      const int swz = (row & 7) << 4;
#pragma unroll
      for (int kk = 0; kk < 2; ++kk)
        bV[kk][ct] = *(const bf16x8*)(sVc + row * 128 + ((kk * 64 + lhi * 16) ^ swz));
    }
    __builtin_amdgcn_s_setprio(1);
#pragma unroll
    for (int qt2 = 0; qt2 < 2; ++qt2) {
      const int q = qt2 * 16 + lrow;
#pragma unroll
      for (int kk = 0; kk < 2; ++kk) {
        const bf16x8 pfrag =
            *(const bf16x8*)(Pw + q * 128 + ((kk * 64 + lhi * 16) ^ ((q & 7) << 4)));
#pragma unroll
        for (int ct = 0; ct < 4; ++ct)
          oacc[qt2][ct] = mfma16(pfrag, bV[kk][ct], oacc[qt2][ct]);
      }
    }
    __builtin_amdgcn_s_setprio(0);

    if (tt < 15) __syncthreads();   // drains prefetch (r2 semantics)
  }

  // ---- epilogue: coalesced unnormalized partial O (f16) via LDS ----
  {
#pragma unroll
    for (int qt2 = 0; qt2 < 2; ++qt2)
#pragma unroll
      for (int ct = 0; ct < 4; ++ct)
#pragma unroll
        for (int r = 0; r < 4; ++r) {
          const int ql = qt2 * 16 + lhi * 4 + r;
          const int c  = ct * 16 + lrow;
          *(f16_t*)(Pw + (ql * 64 + c) * 2) = (f16_t)oacc[qt2][ct][r];
        }
    f16_t* const Ob = Opart + ((size_t)(b * KSPL + ks) * NPIX + q0) * 64;
#pragma unroll
    for (int i = 0; i < 4; ++i) {
      const int idx = i * 64 + lane;        // 256 chunks of 16B, contiguous
      *(f16x8*)(Ob + idx * 8) = *(const f16x8*)(Pw + idx * 16);
    }
  }
  if (lhi < 2) {
    const int q = q0 + lhi * 16 + lrow;
    const size_t base = ((size_t)(b * KSPL + ks) * NPIX + q) * 2;
    mlbuf[base]     = m_run[lhi];
    mlbuf[base + 1] = l_run[lhi];
  }
}

// ========================= stage 3: merge + wout + BN =======================
__global__ __launch_bounds__(256) void merge_out(
    const f16_t* __restrict__ Opart, const float* __restrict__ mlbuf,
    const float* __restrict__ ww,  const float* __restrict__ wb,
    const float* __restrict__ wg,  const float* __restrict__ wbt,
    const float* __restrict__ wm,  const float* __restrict__ wvv,
    float* __restrict__ out)
{
  __shared__ float wlds[128][64];
  __shared__ float bfw[128];
  __shared__ float mrg[32][68];

  const int tid = threadIdx.x;
  const int b   = blockIdx.y;
  const int n0  = blockIdx.x * 32;

  for (int idx = tid; idx < 128 * 64; idx += 256) {
    const int o = idx >> 6, c = idx & 63;
    const float sc = wg[o] * rsqrtf(wvv[o] + EPS);
    wlds[o][c] = ww[o * 64 + c] * sc;
    if (c == 0) bfw[o] = wb[o] * sc + wbt[o] - wm[o] * sc;
  }

  {
    const int px = tid & 31;
    const int cg = tid >> 5;
    const int q  = n0 + px;
    float mk[KSPL], lk[KSPL];
#pragma unroll
    for (int ks = 0; ks < KSPL; ++ks) {
      const size_t base = ((size_t)(b * KSPL + ks) * NPIX + q) * 2;
      mk[ks] = mlbuf[base];
      lk[ks] = mlbuf[base + 1];
    }
    float M = mk[0];
#pragma unroll
    for (int ks = 1; ks < KSPL; ++ks) M = fmaxf(M, mk[ks]);
    float al[KSPL]; float den = 0.f;
#pragma unroll
    for (int ks = 0; ks < KSPL; ++ks) { al[ks] = exp2f(mk[ks] - M); den += al[ks] * lk[ks]; }
    const float inv = 1.f / den;
#pragma unroll
    for (int ks = 0; ks < KSPL; ++ks) al[ks] *= inv;

    float r[8];
#pragma unroll
    for (int j = 0; j < 8; ++j) r[j] = 0.f;
#pragma unroll
    for (int ks = 0; ks < KSPL; ++ks) {
      const f16x8 p = *(const f16x8*)(Opart +
          ((size_t)(b * KSPL + ks) * NPIX + q) * 64 + cg * 8);
#pragma unroll
      for (int j = 0; j < 8; ++j) r[j] += (float)p[j] * al[ks];
    }
#pragma unroll
    for (int j = 0; j < 8; ++j) mrg[px][cg * 8 + j] = r[j];
  }
  __syncthreads();

  const int px = tid & 31;
  const int oh = tid >> 5;
  float acc[16];
#pragma unroll
  for (int j = 0; j < 16; ++j) acc[j] = 0.f;

#pragma unroll 4
  for (int c0 = 0; c0 < 64; c0 += 4) {
    const f32x4 m4 = *(const f32x4*)&mrg[px][c0];
#pragma unroll
    for (int j = 0; j < 16; ++j) {
      const f32x4 w4 = *(const f32x4*)&wlds[oh * 16 + j][c0];
      acc[j] += w4[0] * m4[0] + w4[1] * m4[1] + w4[2] * m4[2] + w4[3] * m4[3];
    }
  }
#pragma unroll
  for (int j = 0; j < 16; ++j) {
    const int o = oh * 16 + j;
    out[((size_t)b * 256 + o) * NPIX + n0 + px] = acc[j] + bfw[o];
  }
}

// ============================== launcher ====================================
extern "C" void kernel_launch(void* const* d_in, const int* in_sizes, int n_in,
                              void* d_out, int out_size, void* d_ws, size_t ws_size,
                              hipStream_t stream) {
  (void)in_sizes; (void)n_in; (void)out_size; (void)ws_size;
  const float* x1  = (const float*)d_in[0];
  const float* x2  = (const float*)d_in[1];
  const float* tw  = (const float*)d_in[2];
  const float* tb  = (const float*)d_in[3];
  const float* tg  = (const float*)d_in[4];
  const float* tbt = (const float*)d_in[5];
  const float* tm  = (const float*)d_in[6];
  const float* tv  = (const float*)d_in[7];
  const float* pw  = (const float*)d_in[8];
  const float* pb  = (const float*)d_in[9];
  const float* pg  = (const float*)d_in[10];
  const float* pbt = (const float*)d_in[11];
  const float* pm  = (const float*)d_in[12];
  const float* pv  = (const float*)d_in[13];
  const float* gw  = (const float*)d_in[14];
  const float* gb  = (const float*)d_in[15];
  const float* gg  = (const float*)d_in[16];
  const float* gbt = (const float*)d_in[17];
  const float* gmn = (const float*)d_in[18];
  const float* gv  = (const float*)d_in[19];
  const float* ww  = (const float*)d_in[20];
  const float* wb  = (const float*)d_in[21];
  const float* wg  = (const float*)d_in[22];
  const float* wbt = (const float*)d_in[23];
  const float* wm  = (const float*)d_in[24];
  const float* wv  = (const float*)d_in[25];

  float* out = (float*)d_out;
  char*  ws  = (char*)d_ws;
  bf16_t* thetaT_h = (bf16_t*)(ws);
  bf16_t* thetaT_l = (bf16_t*)(ws + (size_t)(2)  * 1048576);
  bf16_t* phiT_h   = (bf16_t*)(ws + (size_t)(4)  * 1048576);
  bf16_t* phiT_l   = (bf16_t*)(ws + (size_t)(6)  * 1048576);
  bf16_t* g_cm     = (bf16_t*)(ws + (size_t)(8)  * 1048576);
  f16_t*  Opart    = (f16_t*) (ws + (size_t)(10) * 1048576);
  float*  mlbuf    = (float*) (ws + (size_t)(18) * 1048576);

  dim3 gp(128, 4);
  proj_all<<<gp, 256, 0, stream>>>(x1, x2,
                                   tw, tb, tg, tbt, tm, tv,
                                   pw, pb, pg, pbt, pm, pv,
                                   gw, gb, gg, gbt, gmn, gv,
                                   thetaT_h, thetaT_l, phiT_h, phiT_l,
                                   g_cm, out);
  flash_attn<<<512, 256, 0, stream>>>(thetaT_h, thetaT_l, phiT_h, phiT_l,
                                      g_cm, Opart, mlbuf);
  merge_out<<<gp, 256, 0, stream>>>(Opart, mlbuf, ww, wb, wg, wbt, wm, wv, out);
}